// Round 14
// baseline (200.784 us; speedup 1.0000x reference)
//
#include <hip/hip_runtime.h>
#include <hip/hip_bf16.h>
#include <hip/hip_cooperative_groups.h>

namespace cg = cooperative_groups;

#define NPTS 8192
#define NB   4
#define NQI  8                    // (batch, side) pairs
#define BLK  256
#define CGRID 512                 // cooperative grid: 2 blocks/CU
#define NUNIT 1024                // knn units (qi x qg x sl)
#define RREG 1024                 // raw points per compact region
#define NREG 8                    // regions per qi
#define QG   4                    // query groups (2 regions) per qi
#define NSL  32                   // search slices = 8 regions x 4 subs
#define LMAX 256                  // max staged search pts per slice
#define THR  3.33f

// ctl word layout ([0,320) zeroed by fallback compact block 0; coop path
// uses only bcnt/psum/pcnt, all plain-stored before read across grid.sync):
//   ticket1[qi] @ qi*32 ; ticket2 @ 256 ; meanv[8] f32 @ 288
//   psum[32] f32 @ 320 ; pcnt[32] f32 @ 384 ; bcnt[qi][reg] @ 448
#define W_T2   256
#define W_MEAN 288
#define W_PSUM 320
#define W_PCNT 384
#define W_BCNT 448
#define OFF_PART 4096
#define OFF_PTS  (4096 + (size_t)NQI * NSL * NPTS * 4)   // part = 8 MB

__device__ __forceinline__ void load_pt(int side, int g,
    const float* __restrict__ Ps, const float* __restrict__ Pd,
    const float* __restrict__ F,  const int* __restrict__ Ms,
    const int* __restrict__ Md,
    float& x, float& y, float& z, bool& v)
{
    if (side == 0) {               // warped src
        x = Ps[3*g+0] + F[3*g+0];
        y = Ps[3*g+1] + F[3*g+1];
        z = Ps[3*g+2] + F[3*g+2];
        v = Ms[g] > 0;
    } else {                       // dst
        x = Pd[3*g+0]; y = Pd[3*g+1]; z = Pd[3*g+2];
        v = Md[g] > 0;
    }
}

// region-pack compact body (one region of one qi)
__device__ __forceinline__ void compact_body(
    int qi, int reg,
    const float* __restrict__ Ps, const float* __restrict__ Pd,
    const float* __restrict__ F,  const int* __restrict__ Ms,
    const int* __restrict__ Md,   float4* __restrict__ pts,
    unsigned* __restrict__ ctl,   int* wc, int tid, int lane, int w)
{
    const int b = qi >> 1, side = qi & 1;
    float xx[4], yy[4], zz[4]; bool vv[4];
#pragma unroll
    for (int k = 0; k < 4; ++k) {
        const int g = b * NPTS + reg * RREG + k * BLK + tid;
        load_pt(side, g, Ps, Pd, F, Ms, Md, xx[k], yy[k], zz[k], vv[k]);
    }
    int c = 0;
#pragma unroll
    for (int k = 0; k < 4; ++k) c += vv[k];
    int p = c;
#pragma unroll
    for (int o = 1; o < 64; o <<= 1) {
        int t = __shfl_up(p, o);
        if (lane >= o) p += t;
    }
    if (lane == 63) wc[w] = p;
    __syncthreads();
    int base = p - c;
#pragma unroll
    for (int i = 0; i < 4; ++i) if (i < w) base += wc[i];
#pragma unroll
    for (int k = 0; k < 4; ++k)
        if (vv[k]) {
            pts[(size_t)qi * NPTS + reg * RREG + base] =
                make_float4(xx[k], yy[k], zz[k],
                    fmaf(xx[k], xx[k], fmaf(yy[k], yy[k], zz[k] * zz[k])));
            ++base;
        }
    if (tid == 0)
        ctl[W_BCNT + qi * NREG + reg] =
            (unsigned)(wc[0] + wc[1] + wc[2] + wc[3]);
}

// dense inner loop: KMAX queries/thread vs len staged search pts (broadcast)
template<int KMAX>
__device__ __forceinline__ void inner_loop(
    const float4* __restrict__ pts, size_t qb0, size_t qb1, int n0, int nq,
    const float4* __restrict__ sp, int len, float* __restrict__ pb, int tid)
{
    float qx[KMAX], qy[KMAX], qz[KMAX], bt[KMAX];
#pragma unroll
    for (int k = 0; k < KMAX; ++k) {
        const int q = k * BLK + tid;
        const size_t idx = (q < nq) ? (q < n0 ? qb0 + q : qb1 + (q - n0)) : qb0;
        const float4 p = pts[idx];             // coalesced float4
        qx[k] = p.x; qy[k] = p.y; qz[k] = p.z;
        bt[k] = -1e30f;
    }
#pragma unroll 4
    for (int j = 0; j < len; ++j) {
        const float4 s = sp[j];                // wave-uniform -> LDS broadcast
#pragma unroll
        for (int k = 0; k < KMAX; ++k) {
            float t = fmaf(qx[k], s.x, s.w);
            t = fmaf(qy[k], s.y, t);
            t = fmaf(qz[k], s.z, t);
            bt[k] = fmaxf(bt[k], t);
        }
    }
#pragma unroll
    for (int k = 0; k < KMAX; ++k) {
        const int q = k * BLK + tid;
        if (q < nq) pb[q] = bt[k];             // coalesced plain store
    }
}

// knn unit body (one (qi,qg,sl) unit)
__device__ __forceinline__ void knn_body(
    int qi, int qg, int sl, const float4* __restrict__ pts,
    const unsigned* __restrict__ ctl, float* __restrict__ part,
    float4* sp, int tid)
{
    const int si = qi ^ 1;
    const int n0 = (int)ctl[W_BCNT + qi * NREG + 2 * qg];
    const int n1 = (int)ctl[W_BCNT + qi * NREG + 2 * qg + 1];
    const int nq = n0 + n1;
    if (nq == 0) return;                       // block-uniform

    const int sreg = sl >> 2, sub = sl & 3;
    const int nsr = (int)ctl[W_BCNT + si * NREG + sreg];
    const int L = (nsr + 3) >> 2;
    const int start = sub * L;
    int len = nsr - start; if (len > L) len = L; if (len < 0) len = 0;

    if (tid < len) {
        const float4 p = pts[(size_t)si * NPTS + sreg * RREG + start + tid];
        sp[tid] = make_float4(2.f * p.x, 2.f * p.y, 2.f * p.z, -p.w);
    }
    __syncthreads();

    const size_t qb0 = (size_t)qi * NPTS + (size_t)(2 * qg) * RREG;
    const size_t qb1 = qb0 + RREG;
    float* pb = part + ((size_t)qi * NSL + sl) * NPTS + (size_t)qg * (2 * RREG);
    switch ((nq + BLK - 1) >> 8) {             // block-uniform KMAX dispatch
        case 1: inner_loop<1>(pts, qb0, qb1, n0, nq, sp, len, pb, tid); break;
        case 2: inner_loop<2>(pts, qb0, qb1, n0, nq, sp, len, pb, tid); break;
        case 3: inner_loop<3>(pts, qb0, qb1, n0, nq, sp, len, pb, tid); break;
        case 4: inner_loop<4>(pts, qb0, qb1, n0, nq, sp, len, pb, tid); break;
        case 5: inner_loop<5>(pts, qb0, qb1, n0, nq, sp, len, pb, tid); break;
        case 6: inner_loop<6>(pts, qb0, qb1, n0, nq, sp, len, pb, tid); break;
        case 7: inner_loop<7>(pts, qb0, qb1, n0, nq, sp, len, pb, tid); break;
        case 8: inner_loop<8>(pts, qb0, qb1, n0, nq, sp, len, pb, tid); break;
        default: break;
    }
}

// combine body: per (qi,qg) sum/count of thresholded mins
__device__ __forceinline__ void combine_body(
    int qi, int qg, const float4* __restrict__ pts,
    const float* __restrict__ part, const unsigned* __restrict__ ctl,
    float* red, float& S, float& C, int tid, int lane, int w)
{
    const int n0 = (int)ctl[W_BCNT + qi * NREG + 2 * qg];
    const int n1 = (int)ctl[W_BCNT + qi * NREG + 2 * qg + 1];
    const int nq = n0 + n1;
    const size_t qb0 = (size_t)qi * NPTS + (size_t)(2 * qg) * RREG;
    const size_t qb1 = qb0 + RREG;
    const float* pr = part + (size_t)qi * NSL * NPTS + (size_t)qg * (2 * RREG);
    float s = 0.f, c = 0.f;
#pragma unroll
    for (int k = 0; k < 8; ++k) {
        const int q = k * BLK + tid;
        if (q < nq) {
            float m = -1e30f;
#pragma unroll
            for (int sl = 0; sl < NSL; ++sl)
                m = fmaxf(m, pr[(size_t)sl * NPTS + q]);   // coalesced
            const size_t idx = (q < n0) ? qb0 + q : qb1 + (q - n0);
            const float dd = fmaxf(pts[idx].w - m, 0.f);
            if (dd < THR) { s += dd; c += 1.f; }
        }
    }
#pragma unroll
    for (int off = 32; off; off >>= 1) {
        s += __shfl_down(s, off);
        c += __shfl_down(c, off);
    }
    if (lane == 0) { red[w] = s; red[4 + w] = c; }
    __syncthreads();
    S = red[0] + red[1] + red[2] + red[3];
    C = red[4] + red[5] + red[6] + red[7];
}

// ============================ cooperative path =============================
__global__ __launch_bounds__(BLK, 2) void coop_kernel(
    const float* __restrict__ Ps, const float* __restrict__ Pd,
    const float* __restrict__ F,  const int* __restrict__ Ms,
    const int* __restrict__ Md,   float* __restrict__ part,
    unsigned* __restrict__ ctl,   float4* __restrict__ pts,
    float* __restrict__ out)
{
    cg::grid_group grid = cg::this_grid();
    const int bid = blockIdx.x;
    const int tid = threadIdx.x, lane = tid & 63, w = tid >> 6;
    __shared__ float4 sp[LMAX];
    __shared__ int wc[4];
    __shared__ float red[8];

    // A: compact (64 of 512 blocks)
    if (bid < NQI * NREG)
        compact_body(bid >> 3, bid & 7, Ps, Pd, F, Ms, Md, pts, ctl,
                     wc, tid, lane, w);
    grid.sync();

    // B: knn, 2 units per block
#pragma unroll
    for (int it = 0; it < 2; ++it) {
        const int u = bid + CGRID * it;
        __syncthreads();                       // sp reuse guard
        knn_body(u >> 7, (u >> 5) & 3, u & 31, pts, ctl, part, sp, tid);
    }
    grid.sync();

    // C: per-(qi,qg) partials (32 blocks), plain stores
    if (bid < NQI * QG) {
        float S, C;
        combine_body(bid >> 2, bid & 3, pts, part, ctl, red, S, C,
                     tid, lane, w);
        if (tid == 0) {
            ((float*)(ctl + W_PSUM))[bid] = S;
            ((float*)(ctl + W_PCNT))[bid] = C;
        }
    }
    grid.sync();

    // D: block 0 writes the scalar
    if (bid == 0) {
        float a = 0.f;
        if (tid < NQI) {
            const float* psum = (const float*)(ctl + W_PSUM);
            const float* pcnt = (const float*)(ctl + W_PCNT);
            float S = 0.f, C = 0.f;
#pragma unroll
            for (int g = 0; g < QG; ++g) {
                S += psum[tid * QG + g];
                C += pcnt[tid * QG + g];
            }
            a = S / C;
        }
#pragma unroll
        for (int off = 4; off; off >>= 1) a += __shfl_down(a, off);
        if (tid == 0) out[0] = a;
    }
}

// ============================ fallback path (R12, proven) ==================
__global__ __launch_bounds__(BLK) void compact_kernel(
    const float* __restrict__ Ps, const float* __restrict__ Pd,
    const float* __restrict__ F,  const int* __restrict__ Ms,
    const int* __restrict__ Md,   float4* __restrict__ pts,
    unsigned* __restrict__ ctl)
{
    const int b = blockIdx.z, side = blockIdx.y, r = blockIdx.x;
    const int qi = b * 2 + side;
    const int tid = threadIdx.x, lane = tid & 63, w = tid >> 6;
    __shared__ int wc[4];
    if (r == 0 && side == 0 && b == 0)
        for (int i = tid; i < 320; i += BLK) ctl[i] = 0;
    compact_body(qi, r, Ps, Pd, F, Ms, Md, pts, ctl, wc, tid, lane, w);
}

__global__ __launch_bounds__(BLK) void knn_kernel(
    const float4* __restrict__ pts, const unsigned* __restrict__ ctl,
    float* __restrict__ part)
{
    const int b = blockIdx.z, dir = blockIdx.y;
    const int qg = blockIdx.x >> 5, sl = blockIdx.x & 31;
    __shared__ float4 sp[LMAX];
    knn_body(b * 2 + dir, qg, sl, pts, ctl, part, sp, threadIdx.x);
}

__global__ __launch_bounds__(BLK) void final_kernel(
    const float4* __restrict__ pts, const float* __restrict__ part,
    unsigned* __restrict__ ctl, float* __restrict__ out)
{
    const int b = blockIdx.z, dir = blockIdx.y, qg = blockIdx.x;
    const int qi = b * 2 + dir;
    const int tid = threadIdx.x, lane = tid & 63, w = tid >> 6;
    __shared__ float red[8];
    float S, C;
    combine_body(qi, qg, pts, part, ctl, red, S, C, tid, lane, w);
    if (tid == 0) {
        float* psum  = (float*)(ctl + W_PSUM);
        float* pcnt  = (float*)(ctl + W_PCNT);
        float* meanv = (float*)(ctl + W_MEAN);
        psum[qi * QG + qg] = S;
        pcnt[qi * QG + qg] = C;
        const unsigned r1 = __hip_atomic_fetch_add(&ctl[qi * 32], 1u,
                               __ATOMIC_ACQ_REL, __HIP_MEMORY_SCOPE_AGENT);
        if (r1 == QG - 1) {
            float SS = 0.f, CC = 0.f;
#pragma unroll
            for (int g = 0; g < QG; ++g) {
                SS += psum[qi * QG + g];
                CC += pcnt[qi * QG + g];
            }
            meanv[qi] = SS / CC;
            const unsigned r2 = __hip_atomic_fetch_add(&ctl[W_T2], 1u,
                                   __ATOMIC_ACQ_REL, __HIP_MEMORY_SCOPE_AGENT);
            if (r2 == NQI - 1) {
                float a = 0.f;
#pragma unroll
                for (int i = 0; i < NQI; ++i) a += meanv[i];
                out[0] = a;
            }
        }
    }
}

extern "C" void kernel_launch(void* const* d_in, const int* in_sizes, int n_in,
                              void* d_out, int out_size, void* d_ws, size_t ws_size,
                              hipStream_t stream)
{
    const float* Ps = (const float*)d_in[0];   // points_src  [B,N,3]
    const float* Pd = (const float*)d_in[1];   // points_dst  [B,N,3]
    const float* F  = (const float*)d_in[2];   // flows_pred  [B,N,3]
    // d_in[3] = flows_gt (unused by reference)
    const int* Ms = (const int*)d_in[4];       // masks_src [B,N]
    const int* Md = (const int*)d_in[5];       // masks_dst [B,N]
    float* out = (float*)d_out;

    unsigned* ctl = (unsigned*)d_ws;
    float* part = (float*)((char*)d_ws + OFF_PART);
    float4* pts = (float4*)((char*)d_ws + OFF_PTS);

    void* args[] = { (void*)&Ps, (void*)&Pd, (void*)&F, (void*)&Ms, (void*)&Md,
                     (void*)&part, (void*)&ctl, (void*)&pts, (void*)&out };
    hipError_t e = hipLaunchCooperativeKernel((const void*)coop_kernel,
                                              dim3(CGRID), dim3(BLK),
                                              args, 0, stream);
    if (e != hipSuccess) {                     // deterministic fallback (R12)
        compact_kernel<<<dim3(NREG, 2, NB), BLK, 0, stream>>>(
            Ps, Pd, F, Ms, Md, pts, ctl);
        knn_kernel<<<dim3(QG * NSL, 2, NB), BLK, 0, stream>>>(pts, ctl, part);
        final_kernel<<<dim3(QG, 2, NB), BLK, 0, stream>>>(pts, part, ctl, out);
    }
}